// Round 11
// baseline (776.603 us; speedup 1.0000x reference)
//
#include <hip/hip_runtime.h>
#include <hip/hip_bf16.h>
#include <hip/hip_fp16.h>

#define NG 512  // NUM_GRAPHS
#define EPS_BN 1e-5f

typedef unsigned short ushort_t;
typedef unsigned int uint_t;

__device__ __forceinline__ float4 f4add(float4 a, float4 b) {
    a.x += b.x; a.y += b.y; a.z += b.z; a.w += b.w; return a;
}
__device__ __forceinline__ float4 f4fma(float s, float4 b, float4 a) {
    a.x = fmaf(s, b.x, a.x); a.y = fmaf(s, b.y, a.y);
    a.z = fmaf(s, b.z, a.z); a.w = fmaf(s, b.w, a.w); return a;
}
__device__ __forceinline__ float4 f4scale(float s, float4 a) {
    a.x *= s; a.y *= s; a.z *= s; a.w *= s; return a;
}
__device__ __forceinline__ float4 bnrelu4(float4 v, float4 sc, float4 sh) {
    float4 r;
    r.x = fmaxf(fmaf(sc.x, v.x, sh.x), 0.f);
    r.y = fmaxf(fmaf(sc.y, v.y, sh.y), 0.f);
    r.z = fmaxf(fmaf(sc.z, v.z, sh.z), 0.f);
    r.w = fmaxf(fmaf(sc.w, v.w, sh.w), 0.f);
    return r;
}
__device__ __forceinline__ void bnparam(float sm, float sq, float ga, float bt,
                                        float invN, float& sc, float& sh) {
    float m = sm * invN;
    float var = fmaf(-m, m, sq * invN);
    sc = ga * rsqrtf(var + EPS_BN);
    sh = fmaf(-m, sc, bt);
}

// fp16 helpers: 4 channels (8 B) per load/store
__device__ __forceinline__ float4 ldh4(const ushort_t* p) {
    uint2 u = *reinterpret_cast<const uint2*>(p);
    __half2 a = *reinterpret_cast<const __half2*>(&u.x);
    __half2 b = *reinterpret_cast<const __half2*>(&u.y);
    float2 fa = __half22float2(a), fb = __half22float2(b);
    float4 r; r.x = fa.x; r.y = fa.y; r.z = fb.x; r.w = fb.y; return r;
}
__device__ __forceinline__ void sth4(ushort_t* p, float4 v) {
    __half2 a = __float22half2_rn(make_float2(v.x, v.y));
    __half2 b = __float22half2_rn(make_float2(v.z, v.w));
    uint2 u;
    u.x = *reinterpret_cast<uint_t*>(&a);
    u.y = *reinterpret_cast<uint_t*>(&b);
    *reinterpret_cast<uint2*>(p) = u;
}

// ---------------- degree / normalization ----------------

__global__ void k_count(const int* __restrict__ dst, int* __restrict__ cnt, int E) {
    int i = blockIdx.x * blockDim.x + threadIdx.x;
    if (i < E) atomicAdd(&cnt[dst[i]], 1);
}

__global__ void k_dinv(const int* __restrict__ cnt, float* __restrict__ dinv, int N) {
    int i = blockIdx.x * blockDim.x + threadIdx.x;
    if (i < N) dinv[i] = rsqrtf((float)cnt[i] + 1.0f);  // +1 self-loop
}

// ---------------- exclusive prefix-sum over cnt -> rowptr ----------------

#define SCAN_T 256
#define SCAN_I 4  // 1024 elements per block

__global__ void k_scan1(const int* __restrict__ in, int* __restrict__ out,
                        int* __restrict__ bsum, int N) {
    __shared__ int lds[SCAN_T];
    int t = threadIdx.x;
    int base = blockIdx.x * (SCAN_T * SCAN_I) + t * SCAN_I;
    int v[SCAN_I];
    int sum = 0;
#pragma unroll
    for (int i = 0; i < SCAN_I; ++i) {
        int idx = base + i;
        v[i] = (idx < N) ? in[idx] : 0;
        sum += v[i];
    }
    lds[t] = sum;
    __syncthreads();
    for (int o = 1; o < SCAN_T; o <<= 1) {
        int a = (t >= o) ? lds[t - o] : 0;
        __syncthreads();
        lds[t] += a;
        __syncthreads();
    }
    int run = lds[t] - sum;
#pragma unroll
    for (int i = 0; i < SCAN_I; ++i) {
        int idx = base + i;
        if (idx < N) out[idx] = run;
        run += v[i];
    }
    if (t == SCAN_T - 1) bsum[blockIdx.x] = lds[SCAN_T - 1];
}

__global__ void k_scan2(int* __restrict__ bs, int nb) {
    __shared__ int lds[SCAN_T];
    int t = threadIdx.x;
    int runbase = 0;
    for (int start = 0; start < nb; start += SCAN_T) {
        int idx = start + t;
        int v = (idx < nb) ? bs[idx] : 0;
        lds[t] = v;
        __syncthreads();
        for (int o = 1; o < SCAN_T; o <<= 1) {
            int a = (t >= o) ? lds[t - o] : 0;
            __syncthreads();
            lds[t] += a;
            __syncthreads();
        }
        if (idx < nb) bs[idx] = runbase + lds[t] - v;
        int tot = lds[SCAN_T - 1];
        __syncthreads();
        runbase += tot;
    }
}

__global__ void k_scan3(int* __restrict__ out, const int* __restrict__ bs, int N) {
    int add = bs[blockIdx.x];
    int base = blockIdx.x * (SCAN_T * SCAN_I) + threadIdx.x * SCAN_I;
#pragma unroll
    for (int i = 0; i < SCAN_I; ++i) {
        int idx = base + i;
        if (idx < N) out[idx] += add;
    }
}

// ---------------- bucket edges by dst (CSR), packed (src, dinv[src]) records ----------------

__global__ void k_bucket(const int* __restrict__ src, const int* __restrict__ dst,
                         const float* __restrict__ dinv, const int* __restrict__ rowptr,
                         int* __restrict__ fill, int2* __restrict__ e2, int E) {
    int e = blockIdx.x * blockDim.x + threadIdx.x;
    if (e >= E) return;
    int d = dst[e], s = src[e];
    int pos = rowptr[d] + atomicAdd(&fill[d], 1);
    e2[pos] = make_int2(s, __float_as_int(dinv[s]));
}

// ---------------- fused layer 1: edge-parallel gather raw x (C=6) + mm 6->32 + stats ----------------
// x working set is 2.4 MB (fits per-XCD L2). Output written in 2x16-channel split layout.

template <int COUT>
__global__ __launch_bounds__(256) void k_layer1(
    const int* __restrict__ rowptr, const int* __restrict__ cnt,
    const int2* __restrict__ e2, const float* __restrict__ dinv,
    const float* __restrict__ x, const float* __restrict__ W,
    ushort_t* __restrict__ hout, float* __restrict__ sums,
    float* __restrict__ sumsq, int N) {
    constexpr int NPB = 256;
    constexpr int CG = COUT / 4;   // 8
    constexpr int RPB = 256 / CG;  // 32
    constexpr int ECAP1 = 4608;
    __shared__ float inT[NPB * 6];
    __shared__ float4 wT[6 * CG];
    __shared__ float4 red[256];
    __shared__ int2 eLDS[ECAP1];
    int t = threadIdx.x;
    const float4* W4 = (const float4*)W;
    for (int i = t; i < 6 * CG; i += 256) wT[i] = W4[i];
    int base = blockIdx.x * NPB;
    int lastn = min(base + NPB, N) - 1;
    int eBeg = rowptr[base];
    int eEnd = rowptr[lastn] + cnt[lastn];
    int M = eEnd - eBeg;
    bool useL = (M <= ECAP1);
    if (useL) {
        for (int i = t; i < M; i += 256) eLDS[i] = e2[eBeg + i];
    }
    __syncthreads();
    {
        const float2* x2 = (const float2*)x;
        int ew = t & 3;
        int nl0 = t >> 2;
#pragma unroll 1
        for (int it = 0; it < 4; ++it) {
            int nl = it * 64 + nl0;
            int n = base + nl;
            float a0 = 0, a1 = 0, a2 = 0, a3 = 0, a4 = 0, a5 = 0;
            float di = 0.f;
            if (n < N) {
                di = dinv[n];
                int beg = rowptr[n], end = beg + cnt[n];
                if (ew == 0) {
                    size_t b3 = (size_t)n * 3;
                    float2 p0 = x2[b3], p1 = x2[b3 + 1], p2 = x2[b3 + 2];
                    a0 = di * p0.x; a1 = di * p0.y; a2 = di * p1.x;
                    a3 = di * p1.y; a4 = di * p2.x; a5 = di * p2.y;
                }
                if (useL) {
                    int r = beg - eBeg + ew, re = end - eBeg;
                    for (; r + 4 < re; r += 8) {
                        int2 pa = eLDS[r], pb = eLDS[r + 4];
                        size_t sa = (size_t)pa.x * 3, sb = (size_t)pb.x * 3;
                        float2 qa0 = x2[sa], qa1 = x2[sa + 1], qa2 = x2[sa + 2];
                        float2 qb0 = x2[sb], qb1 = x2[sb + 1], qb2 = x2[sb + 2];
                        __builtin_amdgcn_sched_barrier(0);
                        float wa = __int_as_float(pa.y), wb = __int_as_float(pb.y);
                        a0 = fmaf(wa, qa0.x, a0); a1 = fmaf(wa, qa0.y, a1);
                        a2 = fmaf(wa, qa1.x, a2); a3 = fmaf(wa, qa1.y, a3);
                        a4 = fmaf(wa, qa2.x, a4); a5 = fmaf(wa, qa2.y, a5);
                        a0 = fmaf(wb, qb0.x, a0); a1 = fmaf(wb, qb0.y, a1);
                        a2 = fmaf(wb, qb1.x, a2); a3 = fmaf(wb, qb1.y, a3);
                        a4 = fmaf(wb, qb2.x, a4); a5 = fmaf(wb, qb2.y, a5);
                    }
                    if (r < re) {
                        int2 pa = eLDS[r];
                        size_t sa = (size_t)pa.x * 3;
                        float2 qa0 = x2[sa], qa1 = x2[sa + 1], qa2 = x2[sa + 2];
                        float wa = __int_as_float(pa.y);
                        a0 = fmaf(wa, qa0.x, a0); a1 = fmaf(wa, qa0.y, a1);
                        a2 = fmaf(wa, qa1.x, a2); a3 = fmaf(wa, qa1.y, a3);
                        a4 = fmaf(wa, qa2.x, a4); a5 = fmaf(wa, qa2.y, a5);
                    }
                } else {
                    for (int e = beg + ew; e < end; e += 4) {
                        int2 pa = e2[e];
                        size_t sa = (size_t)pa.x * 3;
                        float2 qa0 = x2[sa], qa1 = x2[sa + 1], qa2 = x2[sa + 2];
                        float wa = __int_as_float(pa.y);
                        a0 = fmaf(wa, qa0.x, a0); a1 = fmaf(wa, qa0.y, a1);
                        a2 = fmaf(wa, qa1.x, a2); a3 = fmaf(wa, qa1.y, a3);
                        a4 = fmaf(wa, qa2.x, a4); a5 = fmaf(wa, qa2.y, a5);
                    }
                }
            }
#pragma unroll
            for (int m = 1; m < 4; m <<= 1) {
                a0 += __shfl_xor(a0, m); a1 += __shfl_xor(a1, m);
                a2 += __shfl_xor(a2, m); a3 += __shfl_xor(a3, m);
                a4 += __shfl_xor(a4, m); a5 += __shfl_xor(a5, m);
            }
            if (ew == 0 && n < N) {
                int o = nl * 6;
                inT[o + 0] = di * a0; inT[o + 1] = di * a1; inT[o + 2] = di * a2;
                inT[o + 3] = di * a3; inT[o + 4] = di * a4; inT[o + 5] = di * a5;
            }
        }
    }
    __syncthreads();
    int gi = t % CG, r0 = t / CG, c0 = gi * 4;
    int nrows = min(NPB, N - base);
    float4 s = {0, 0, 0, 0}, s2 = {0, 0, 0, 0};
    // output split layout: half = c0/16, 16 ch per half
    size_t hoff = (size_t)(c0 / 16) * (size_t)N * 16 + (size_t)(c0 % 16);
    for (int r = r0; r < nrows; r += RPB) {
        const float* row = inT + r * 6;
        float4 acc = {0, 0, 0, 0};
#pragma unroll
        for (int k = 0; k < 6; ++k) acc = f4fma(row[k], wT[k * CG + gi], acc);
        sth4(hout + hoff + (size_t)(base + r) * 16, acc);
        s = f4add(s, acc);
        s2.x = fmaf(acc.x, acc.x, s2.x);
        s2.y = fmaf(acc.y, acc.y, s2.y);
        s2.z = fmaf(acc.z, acc.z, s2.z);
        s2.w = fmaf(acc.w, acc.w, s2.w);
    }
    red[t] = s;
    for (int hh = RPB / 2; hh > 0; hh >>= 1) {
        __syncthreads();
        if (r0 < hh) red[t] = f4add(red[t], red[t + hh * CG]);
    }
    if (r0 == 0) {
        float4 a = red[t];
        atomicAdd(&sums[c0 + 0], a.x); atomicAdd(&sums[c0 + 1], a.y);
        atomicAdd(&sums[c0 + 2], a.z); atomicAdd(&sums[c0 + 3], a.w);
    }
    __syncthreads();
    red[t] = s2;
    for (int hh = RPB / 2; hh > 0; hh >>= 1) {
        __syncthreads();
        if (r0 < hh) red[t] = f4add(red[t], red[t + hh * CG]);
    }
    if (r0 == 0) {
        float4 b = red[t];
        atomicAdd(&sumsq[c0 + 0], b.x); atomicAdd(&sumsq[c0 + 1], b.y);
        atomicAdd(&sumsq[c0 + 2], b.z); atomicAdd(&sumsq[c0 + 3], b.w);
    }
}

// ---------------- fused layer: split-gather(+BN_prev+ReLU) + mm CIN->COUT + stats ----------------
// hin is stored as ISPLIT slabs of [N][CIN/ISPLIT] fp16 (16 ch = 3.2 MB per slab: fits
// per-XCD 4MB L2). The gather runs ISPLIT sequential passes, each touching one slab ->
// high L2 hit rate. hout written as OSPLIT slabs (OSPLIT=1 -> linear).

template <int CIN, int COUT, int NPB, int ISPLIT, int OSPLIT>
__global__ __launch_bounds__(256, 4) void k_layer(
    const int* __restrict__ rowptr, const int* __restrict__ cnt,
    const int2* __restrict__ e2, const float* __restrict__ dinv,
    const ushort_t* __restrict__ hin,
    const float* __restrict__ sums_in, const float* __restrict__ sumsq_in,
    const float* __restrict__ gam, const float* __restrict__ bet,
    const float* __restrict__ W, ushort_t* __restrict__ hout,
    float* __restrict__ sums_out, float* __restrict__ sumsq_out,
    int N, float invN) {
    constexpr int CINP = CIN / ISPLIT;   // channels per gather pass (16)
    constexpr int TPN = CINP / 4;        // lanes per node per pass (4)
    constexpr int PAD = CIN / 4 + 1;     // padded row stride in float4
    constexpr int NPI = 256 / TPN;       // nodes per iteration (64)
    constexpr int ITERP = NPB * TPN / 256;
    constexpr int CG = COUT / 4;
    constexpr int RPB = 256 / CG;
    constexpr int CPSO = COUT / OSPLIT;  // channels per output slab
    constexpr int ECAP = 2048;
    __shared__ float4 inT4[NPB * PAD];
    __shared__ float4 red[256];
    __shared__ int2 eLDS[ECAP];
    int t = threadIdx.x;
    const float4* W4 = (const float4*)W;
    int base = blockIdx.x * NPB;
    int lastn = min(base + NPB, N) - 1;
    int eBeg = rowptr[base];
    int eEnd = rowptr[lastn] + cnt[lastn];
    int M = eEnd - eBeg;
    bool useL = (M <= ECAP);
    if (useL) {
        for (int i = t; i < M; i += 256) eLDS[i] = e2[eBeg + i];
    }
    __syncthreads();
    // ---- phase 1: ISPLIT gather passes, one 3.2MB slab each ----
    {
        int c4 = t % TPN;
        int co = c4 * 4;  // channel offset within pass
#pragma unroll 1
        for (int sp = 0; sp < ISPLIT; ++sp) {
            int gc4 = sp * TPN + c4;  // global float4 channel index
            float4 sm = reinterpret_cast<const float4*>(sums_in)[gc4];
            float4 sq = reinterpret_cast<const float4*>(sumsq_in)[gc4];
            float4 ga = reinterpret_cast<const float4*>(gam)[gc4];
            float4 bt = reinterpret_cast<const float4*>(bet)[gc4];
            float4 sc, sh;
            bnparam(sm.x, sq.x, ga.x, bt.x, invN, sc.x, sh.x);
            bnparam(sm.y, sq.y, ga.y, bt.y, invN, sc.y, sh.y);
            bnparam(sm.z, sq.z, ga.z, bt.z, invN, sc.z, sh.z);
            bnparam(sm.w, sq.w, ga.w, bt.w, invN, sc.w, sh.w);
            const ushort_t* hsp = hin + (size_t)sp * (size_t)N * CINP;
#pragma unroll
            for (int it = 0; it < ITERP; ++it) {
                int nl = it * NPI + t / TPN;
                int n = base + nl;
                if (n < N) {
                    int beg = rowptr[n], end = beg + cnt[n];
                    float di = dinv[n];
                    float4 acc = f4scale(di, bnrelu4(ldh4(hsp + (size_t)n * CINP + co), sc, sh));
                    if (useL) {
                        int r = beg - eBeg, re = end - eBeg;
                        for (; r + 7 < re; r += 8) {
                            int2 p0 = eLDS[r],     p1 = eLDS[r + 1];
                            int2 p2_ = eLDS[r + 2], p3_ = eLDS[r + 3];
                            int2 p4 = eLDS[r + 4], p5 = eLDS[r + 5];
                            int2 p6 = eLDS[r + 6], p7 = eLDS[r + 7];
                            float4 v0 = ldh4(hsp + (size_t)p0.x * CINP + co);
                            float4 v1 = ldh4(hsp + (size_t)p1.x * CINP + co);
                            float4 v2 = ldh4(hsp + (size_t)p2_.x * CINP + co);
                            float4 v3 = ldh4(hsp + (size_t)p3_.x * CINP + co);
                            float4 v4 = ldh4(hsp + (size_t)p4.x * CINP + co);
                            float4 v5 = ldh4(hsp + (size_t)p5.x * CINP + co);
                            float4 v6 = ldh4(hsp + (size_t)p6.x * CINP + co);
                            float4 v7 = ldh4(hsp + (size_t)p7.x * CINP + co);
                            __builtin_amdgcn_sched_barrier(0);
                            acc = f4fma(__int_as_float(p0.y), bnrelu4(v0, sc, sh), acc);
                            acc = f4fma(__int_as_float(p1.y), bnrelu4(v1, sc, sh), acc);
                            acc = f4fma(__int_as_float(p2_.y), bnrelu4(v2, sc, sh), acc);
                            acc = f4fma(__int_as_float(p3_.y), bnrelu4(v3, sc, sh), acc);
                            acc = f4fma(__int_as_float(p4.y), bnrelu4(v4, sc, sh), acc);
                            acc = f4fma(__int_as_float(p5.y), bnrelu4(v5, sc, sh), acc);
                            acc = f4fma(__int_as_float(p6.y), bnrelu4(v6, sc, sh), acc);
                            acc = f4fma(__int_as_float(p7.y), bnrelu4(v7, sc, sh), acc);
                        }
                        for (; r + 3 < re; r += 4) {
                            int2 p0 = eLDS[r], p1 = eLDS[r + 1];
                            int2 p2_ = eLDS[r + 2], p3_ = eLDS[r + 3];
                            float4 v0 = ldh4(hsp + (size_t)p0.x * CINP + co);
                            float4 v1 = ldh4(hsp + (size_t)p1.x * CINP + co);
                            float4 v2 = ldh4(hsp + (size_t)p2_.x * CINP + co);
                            float4 v3 = ldh4(hsp + (size_t)p3_.x * CINP + co);
                            __builtin_amdgcn_sched_barrier(0);
                            acc = f4fma(__int_as_float(p0.y), bnrelu4(v0, sc, sh), acc);
                            acc = f4fma(__int_as_float(p1.y), bnrelu4(v1, sc, sh), acc);
                            acc = f4fma(__int_as_float(p2_.y), bnrelu4(v2, sc, sh), acc);
                            acc = f4fma(__int_as_float(p3_.y), bnrelu4(v3, sc, sh), acc);
                        }
                        for (; r < re; ++r) {
                            int2 p0 = eLDS[r];
                            acc = f4fma(__int_as_float(p0.y),
                                        bnrelu4(ldh4(hsp + (size_t)p0.x * CINP + co), sc, sh), acc);
                        }
                    } else {
                        // overflow fallback (astronomically rare)
                        for (int e = beg; e < end; ++e) {
                            int2 p0 = e2[e];
                            acc = f4fma(__int_as_float(p0.y),
                                        bnrelu4(ldh4(hsp + (size_t)p0.x * CINP + co), sc, sh), acc);
                        }
                    }
                    inT4[nl * PAD + sp * TPN + c4] = f4scale(di, acc);
                }
            }
        }
    }
    __syncthreads();
    // ---- phase 2: mm from LDS (natural channel order), W from global, split fp16 store ----
    int gi = t % CG, r0 = t / CG, c0 = gi * 4;
    int nrows = min(NPB, N - base);
    float4 s = {0, 0, 0, 0}, s2 = {0, 0, 0, 0};
    size_t hoff = (size_t)(c0 / CPSO) * (size_t)N * CPSO + (size_t)(c0 % CPSO);
    for (int r = r0; r < nrows; r += RPB) {
        const float* row = (const float*)(inT4 + r * PAD);
        float4 acc = {0, 0, 0, 0};
#pragma unroll 8
        for (int k = 0; k < CIN; ++k) acc = f4fma(row[k], W4[k * CG + gi], acc);
        sth4(hout + hoff + (size_t)(base + r) * CPSO, acc);
        s = f4add(s, acc);
        s2.x = fmaf(acc.x, acc.x, s2.x);
        s2.y = fmaf(acc.y, acc.y, s2.y);
        s2.z = fmaf(acc.z, acc.z, s2.z);
        s2.w = fmaf(acc.w, acc.w, s2.w);
    }
    red[t] = s;
    for (int hh = RPB / 2; hh > 0; hh >>= 1) {
        __syncthreads();
        if (r0 < hh) red[t] = f4add(red[t], red[t + hh * CG]);
    }
    if (r0 == 0) {
        float4 a = red[t];
        atomicAdd(&sums_out[c0 + 0], a.x); atomicAdd(&sums_out[c0 + 1], a.y);
        atomicAdd(&sums_out[c0 + 2], a.z); atomicAdd(&sums_out[c0 + 3], a.w);
    }
    __syncthreads();
    red[t] = s2;
    for (int hh = RPB / 2; hh > 0; hh >>= 1) {
        __syncthreads();
        if (r0 < hh) red[t] = f4add(red[t], red[t + hh * CG]);
    }
    if (r0 == 0) {
        float4 b = red[t];
        atomicAdd(&sumsq_out[c0 + 0], b.x); atomicAdd(&sumsq_out[c0 + 1], b.y);
        atomicAdd(&sumsq_out[c0 + 2], b.z); atomicAdd(&sumsq_out[c0 + 3], b.w);
    }
}

// ---------------- head matmul (pool @ Wf1) + stats, LDS-tiled ----------------

template <int CIN, int COUT, int ROWS>
__global__ __launch_bounds__(256) void k_mm_stats(
    const float* __restrict__ in, const float* __restrict__ W,
    float* __restrict__ out, float* __restrict__ sums,
    float* __restrict__ sumsq, int N) {
    constexpr int CG = COUT / 4;
    constexpr int RPB = 256 / CG;
    __shared__ float4 inT4[ROWS * CIN / 4];
    float* inT = (float*)inT4;
    __shared__ float4 wT[CIN * CG];
    __shared__ float4 red[256];
    int t = threadIdx.x;
    const float4* W4 = reinterpret_cast<const float4*>(W);
    for (int i = t; i < CIN * CG; i += 256) wT[i] = W4[i];
    int base = blockIdx.x * ROWS;
    int nrows = min(ROWS, N - base);
    {
        const float4* in4 = reinterpret_cast<const float4*>(in + (size_t)base * CIN);
        int tot = nrows * (CIN / 4);
        for (int i = t; i < tot; i += 256) inT4[i] = in4[i];
    }
    __syncthreads();
    int gi = t % CG, r0 = t / CG, c0 = gi * 4;
    float4 s = {0, 0, 0, 0}, s2 = {0, 0, 0, 0};
    for (int r = r0; r < nrows; r += RPB) {
        const float* row = inT + r * CIN;
        float4 acc = {0, 0, 0, 0};
#pragma unroll
        for (int k = 0; k < CIN; ++k) acc = f4fma(row[k], wT[k * CG + gi], acc);
        reinterpret_cast<float4*>(out + (size_t)(base + r) * COUT)[gi] = acc;
        s = f4add(s, acc);
        s2.x = fmaf(acc.x, acc.x, s2.x);
        s2.y = fmaf(acc.y, acc.y, s2.y);
        s2.z = fmaf(acc.z, acc.z, s2.z);
        s2.w = fmaf(acc.w, acc.w, s2.w);
    }
    red[t] = s;
    for (int hh = RPB / 2; hh > 0; hh >>= 1) {
        __syncthreads();
        if (r0 < hh) red[t] = f4add(red[t], red[t + hh * CG]);
    }
    if (r0 == 0) {
        float4 a = red[t];
        atomicAdd(&sums[c0 + 0], a.x); atomicAdd(&sums[c0 + 1], a.y);
        atomicAdd(&sums[c0 + 2], a.z); atomicAdd(&sums[c0 + 3], a.w);
    }
    __syncthreads();
    red[t] = s2;
    for (int hh = RPB / 2; hh > 0; hh >>= 1) {
        __syncthreads();
        if (r0 < hh) red[t] = f4add(red[t], red[t + hh * CG]);
    }
    if (r0 == 0) {
        float4 b = red[t];
        atomicAdd(&sumsq[c0 + 0], b.x); atomicAdd(&sumsq[c0 + 1], b.y);
        atomicAdd(&sumsq[c0 + 2], b.z); atomicAdd(&sumsq[c0 + 3], b.w);
    }
}

// ---------------- segmented segment_max with fused BN+ReLU (batch is sorted) ----------------

__global__ void k_segmax_bn(const ushort_t* __restrict__ h, const int* __restrict__ batch,
                            const float* __restrict__ sums, const float* __restrict__ sumsq,
                            const float* __restrict__ gam, const float* __restrict__ bet,
                            float* __restrict__ pool, int N, float invN) {
    int t = threadIdx.x;
    int c = t & 127;
    int sub = t >> 7;
    int base = blockIdx.x * 64 + sub * 32;
    if (base >= N) return;
    float sc, sh;
    bnparam(sums[c], sumsq[c], gam[c], bet[c], invN, sc, sh);
    int cur = batch[base];
    float h0 = __half2float(*reinterpret_cast<const __half*>(&h[(size_t)base * 128 + c]));
    float mx = fmaxf(fmaf(sc, h0, sh), 0.f);
    int lim = min(32, N - base);
    for (int i = 1; i < lim; ++i) {
        int n = base + i;
        int b = batch[n];
        float hv = __half2float(*reinterpret_cast<const __half*>(&h[(size_t)n * 128 + c]));
        float v = fmaxf(fmaf(sc, hv, sh), 0.f);
        if (b != cur) {
            atomicMax(reinterpret_cast<int*>(pool) + (cur << 7) + c, __float_as_int(mx));
            cur = b; mx = v;
        } else {
            mx = fmaxf(mx, v);
        }
    }
    atomicMax(reinterpret_cast<int*>(pool) + (cur << 7) + c, __float_as_int(mx));
}

// ---------------- head: BN4+ReLU on load, FC2, row-L2-normalize ----------------

__global__ void k_head(const float* __restrict__ Z, const float* __restrict__ sums,
                       const float* __restrict__ sumsq, const float* __restrict__ gam,
                       const float* __restrict__ bet, const float* __restrict__ Wf2,
                       const float* __restrict__ bf2, float* __restrict__ out) {
    int g = blockIdx.x, c = threadIdx.x;  // 64 threads = 1 wave
    __shared__ float row[128];
    const float invG = 1.0f / (float)NG;
    for (int j = c; j < 128; j += 64) {
        float sc, sh;
        bnparam(sums[j], sumsq[j], gam[j], bet[j], invG, sc, sh);
        row[j] = fmaxf(fmaf(sc, Z[(g << 7) + j], sh), 0.f);
    }
    __syncthreads();
    float acc = bf2[c];
#pragma unroll
    for (int k = 0; k < 128; ++k) acc = fmaf(row[k], Wf2[k * 64 + c], acc);
    float ss = acc * acc;
#pragma unroll
    for (int off = 32; off; off >>= 1) ss += __shfl_xor(ss, off);
    out[(g << 6) + c] = acc / fmaxf(sqrtf(ss), 1e-12f);
}

// ---------------- launch ----------------

extern "C" void kernel_launch(void* const* d_in, const int* in_sizes, int n_in,
                              void* d_out, int out_size, void* d_ws, size_t ws_size,
                              hipStream_t stream) {
    const float* x    = (const float*)d_in[0];
    const int*   src  = (const int*)d_in[1];
    const int*   dst  = (const int*)d_in[2];
    const int*   batch= (const int*)d_in[3];
    const float* W1   = (const float*)d_in[4];   // b1 cancels in BN
    const float* g1   = (const float*)d_in[6];
    const float* be1  = (const float*)d_in[7];
    const float* W2   = (const float*)d_in[8];   // b2 cancels
    const float* g2   = (const float*)d_in[10];
    const float* be2  = (const float*)d_in[11];
    const float* W3   = (const float*)d_in[12];  // b3 cancels
    const float* g3   = (const float*)d_in[14];
    const float* be3  = (const float*)d_in[15];
    const float* Wf1  = (const float*)d_in[16];  // bf1 cancels
    const float* g4   = (const float*)d_in[18];
    const float* be4  = (const float*)d_in[19];
    const float* Wf2  = (const float*)d_in[20];
    const float* bf2  = (const float*)d_in[21];
    float* out = (float*)d_out;

    const int N = in_sizes[0] / 6;
    const int E = in_sizes[1];
    const int nScanBlocks = (N + SCAN_T * SCAN_I - 1) / (SCAN_T * SCAN_I);

    // workspace carve-up
    char* ws = (char*)d_ws;
    size_t off = 0;
    auto carve = [&](size_t bytes) {
        void* p = ws + off;
        off += (bytes + 255) & ~(size_t)255;
        return p;
    };
    int*     cnt    = (int*)carve((size_t)N * 4);
    float*   dinv   = (float*)carve((size_t)N * 4);
    int*     rowptr = (int*)carve((size_t)N * 4);
    int*     fill   = (int*)carve((size_t)N * 4);
    int*     bsum   = (int*)carve((size_t)4096 * 4);
    int2*    e2     = (int2*)carve((size_t)E * 8);          // packed (src, dinv[src])
    ushort_t* H1    = (ushort_t*)carve((size_t)N * 32 * 2); // layer-1 out (2 slabs of N*16, fp16)
    ushort_t* H2    = (ushort_t*)carve((size_t)N * 64 * 2); // layer-2 out (4 slabs of N*16, fp16)
    ushort_t* H3    = (ushort_t*)carve((size_t)N * 128 * 2);// layer-3 out (linear fp16)
    float*   stats  = (float*)carve(704 * 4);
    float*   pool   = (float*)carve((size_t)NG * 128 * 4);
    float*   Z      = (float*)carve((size_t)NG * 128 * 4);
    float* s1 = stats;        // L1 sums/sumsq (32+32)
    float* s2 = stats + 64;   // L2 (64+64)
    float* s3 = stats + 192;  // L3 (128+128)
    float* s4 = stats + 448;  // head (128+128)

    const float invN = 1.0f / (float)N;

    // ---- build dst-sorted CSR (once; reused by all 3 layers) ----
    hipMemsetAsync(cnt, 0, (size_t)N * 4, stream);
    hipMemsetAsync(fill, 0, (size_t)N * 4, stream);
    hipMemsetAsync(stats, 0, 704 * 4, stream);
    hipMemsetAsync(pool, 0, (size_t)NG * 128 * 4, stream);
    k_count<<<(E + 255) / 256, 256, 0, stream>>>(dst, cnt, E);
    k_dinv<<<(N + 255) / 256, 256, 0, stream>>>(cnt, dinv, N);
    k_scan1<<<nScanBlocks, SCAN_T, 0, stream>>>(cnt, rowptr, bsum, N);
    k_scan2<<<1, SCAN_T, 0, stream>>>(bsum, nScanBlocks);
    k_scan3<<<nScanBlocks, SCAN_T, 0, stream>>>(rowptr, bsum, N);
    k_bucket<<<(E + 255) / 256, 256, 0, stream>>>(src, dst, dinv, rowptr, fill, e2, E);

    // ---- layer 1 fused: gather x (C=6, 2.4MB WS) + mm 6->32 + stats1 -> H1 (2-slab fp16) ----
    k_layer1<32><<<(N + 255) / 256, 256, 0, stream>>>(
        rowptr, cnt, e2, dinv, x, W1, H1, s1, s1 + 32, N);

    // ---- layer 2 fused: 2-pass split gather (3.2MB slabs) + mm 32->64 -> H2 (4-slab fp16) ----
    k_layer<32, 64, 64, 2, 4><<<(N + 63) / 64, 256, 0, stream>>>(
        rowptr, cnt, e2, dinv, H1, s1, s1 + 32, g1, be1, W2, H2,
        s2, s2 + 64, N, invN);

    // ---- layer 3 fused: 4-pass split gather (3.2MB slabs) + mm 64->128 -> H3 (linear fp16) ----
    k_layer<64, 128, 64, 4, 1><<<(N + 63) / 64, 256, 0, stream>>>(
        rowptr, cnt, e2, dinv, H2, s2, s2 + 64, g2, be2, W3, H3,
        s3, s3 + 128, N, invN);

    // ---- pooling: segmented segment_max with fused BN3+ReLU ----
    k_segmax_bn<<<(N + 63) / 64, 256, 0, stream>>>(H3, batch, s3, s3 + 128, g3, be3, pool, N, invN);

    // ---- head: FC1 (+stats4), then BN4+ReLU+FC2+normalize ----
    k_mm_stats<128, 128, 64><<<(NG + 63) / 64, 256, 0, stream>>>(pool, Wf1, Z, s4, s4 + 128, NG);
    k_head<<<NG, 64, 0, stream>>>(Z, s4, s4 + 128, g4, be4, Wf2, bf2, out);
}

// Round 12
// 751.031 us; speedup vs baseline: 1.0340x; 1.0340x over previous
//
#include <hip/hip_runtime.h>
#include <hip/hip_bf16.h>
#include <hip/hip_fp16.h>

#define NG 512  // NUM_GRAPHS
#define EPS_BN 1e-5f

typedef unsigned short ushort_t;
typedef unsigned int uint_t;

__device__ __forceinline__ float4 f4add(float4 a, float4 b) {
    a.x += b.x; a.y += b.y; a.z += b.z; a.w += b.w; return a;
}
__device__ __forceinline__ float4 f4fma(float s, float4 b, float4 a) {
    a.x = fmaf(s, b.x, a.x); a.y = fmaf(s, b.y, a.y);
    a.z = fmaf(s, b.z, a.z); a.w = fmaf(s, b.w, a.w); return a;
}
__device__ __forceinline__ float4 f4scale(float s, float4 a) {
    a.x *= s; a.y *= s; a.z *= s; a.w *= s; return a;
}
__device__ __forceinline__ float4 bnrelu4(float4 v, float4 sc, float4 sh) {
    float4 r;
    r.x = fmaxf(fmaf(sc.x, v.x, sh.x), 0.f);
    r.y = fmaxf(fmaf(sc.y, v.y, sh.y), 0.f);
    r.z = fmaxf(fmaf(sc.z, v.z, sh.z), 0.f);
    r.w = fmaxf(fmaf(sc.w, v.w, sh.w), 0.f);
    return r;
}
__device__ __forceinline__ void bnparam(float sm, float sq, float ga, float bt,
                                        float invN, float& sc, float& sh) {
    float m = sm * invN;
    float var = fmaf(-m, m, sq * invN);
    sc = ga * rsqrtf(var + EPS_BN);
    sh = fmaf(-m, sc, bt);
}

// fp16 row helpers: load/store 4 channels (8 B) as one uint2
__device__ __forceinline__ float4 ldh4(const ushort_t* p) {
    uint2 u = *reinterpret_cast<const uint2*>(p);
    __half2 a = *reinterpret_cast<const __half2*>(&u.x);
    __half2 b = *reinterpret_cast<const __half2*>(&u.y);
    float2 fa = __half22float2(a), fb = __half22float2(b);
    float4 r; r.x = fa.x; r.y = fa.y; r.z = fb.x; r.w = fb.y; return r;
}
__device__ __forceinline__ void sth4(ushort_t* p, float4 v) {
    __half2 a = __float22half2_rn(make_float2(v.x, v.y));
    __half2 b = __float22half2_rn(make_float2(v.z, v.w));
    uint2 u;
    u.x = *reinterpret_cast<uint_t*>(&a);
    u.y = *reinterpret_cast<uint_t*>(&b);
    *reinterpret_cast<uint2*>(p) = u;
}

// ---------------- degree / normalization ----------------

__global__ void k_count(const int* __restrict__ dst, int* __restrict__ cnt, int E) {
    int i = blockIdx.x * blockDim.x + threadIdx.x;
    if (i < E) atomicAdd(&cnt[dst[i]], 1);
}

__global__ void k_dinv(const int* __restrict__ cnt, float* __restrict__ dinv, int N) {
    int i = blockIdx.x * blockDim.x + threadIdx.x;
    if (i < N) dinv[i] = rsqrtf((float)cnt[i] + 1.0f);  // +1 self-loop
}

// ---------------- exclusive prefix-sum over cnt -> rowptr ----------------

#define SCAN_T 256
#define SCAN_I 4  // 1024 elements per block

__global__ void k_scan1(const int* __restrict__ in, int* __restrict__ out,
                        int* __restrict__ bsum, int N) {
    __shared__ int lds[SCAN_T];
    int t = threadIdx.x;
    int base = blockIdx.x * (SCAN_T * SCAN_I) + t * SCAN_I;
    int v[SCAN_I];
    int sum = 0;
#pragma unroll
    for (int i = 0; i < SCAN_I; ++i) {
        int idx = base + i;
        v[i] = (idx < N) ? in[idx] : 0;
        sum += v[i];
    }
    lds[t] = sum;
    __syncthreads();
    for (int o = 1; o < SCAN_T; o <<= 1) {
        int a = (t >= o) ? lds[t - o] : 0;
        __syncthreads();
        lds[t] += a;
        __syncthreads();
    }
    int run = lds[t] - sum;
#pragma unroll
    for (int i = 0; i < SCAN_I; ++i) {
        int idx = base + i;
        if (idx < N) out[idx] = run;
        run += v[i];
    }
    if (t == SCAN_T - 1) bsum[blockIdx.x] = lds[SCAN_T - 1];
}

__global__ void k_scan2(int* __restrict__ bs, int nb) {
    __shared__ int lds[SCAN_T];
    int t = threadIdx.x;
    int runbase = 0;
    for (int start = 0; start < nb; start += SCAN_T) {
        int idx = start + t;
        int v = (idx < nb) ? bs[idx] : 0;
        lds[t] = v;
        __syncthreads();
        for (int o = 1; o < SCAN_T; o <<= 1) {
            int a = (t >= o) ? lds[t - o] : 0;
            __syncthreads();
            lds[t] += a;
            __syncthreads();
        }
        if (idx < nb) bs[idx] = runbase + lds[t] - v;
        int tot = lds[SCAN_T - 1];
        __syncthreads();
        runbase += tot;
    }
}

__global__ void k_scan3(int* __restrict__ out, const int* __restrict__ bs, int N) {
    int add = bs[blockIdx.x];
    int base = blockIdx.x * (SCAN_T * SCAN_I) + threadIdx.x * SCAN_I;
#pragma unroll
    for (int i = 0; i < SCAN_I; ++i) {
        int idx = base + i;
        if (idx < N) out[idx] += add;
    }
}

// ---------------- bucket edges by dst (CSR), packed (src, dinv[src]) records ----------------

__global__ void k_bucket(const int* __restrict__ src, const int* __restrict__ dst,
                         const float* __restrict__ dinv, const int* __restrict__ rowptr,
                         int* __restrict__ fill, int2* __restrict__ e2, int E) {
    int e = blockIdx.x * blockDim.x + threadIdx.x;
    if (e >= E) return;
    int d = dst[e], s = src[e];
    int pos = rowptr[d] + atomicAdd(&fill[d], 1);
    e2[pos] = make_int2(s, __float_as_int(dinv[s]));
}

// ---------------- fused layer 1: edge-parallel gather raw x (C=6) + mm 6->COUT + stats ----------------
// LDS-staged edge records (kills the idx-load half of the dependent chain).

template <int COUT>
__global__ __launch_bounds__(256) void k_layer1(
    const int* __restrict__ rowptr, const int* __restrict__ cnt,
    const int2* __restrict__ e2, const float* __restrict__ dinv,
    const float* __restrict__ x, const float* __restrict__ W,
    ushort_t* __restrict__ hout, float* __restrict__ sums,
    float* __restrict__ sumsq, int N) {
    constexpr int NPB = 256;
    constexpr int CG = COUT / 4;   // 8
    constexpr int RPB = 256 / CG;  // 32
    constexpr int ECAP1 = 4608;
    __shared__ float inT[NPB * 6];
    __shared__ float4 wT[6 * CG];
    __shared__ float4 red[256];
    __shared__ int2 eLDS[ECAP1];
    int t = threadIdx.x;
    const float4* W4 = (const float4*)W;
    for (int i = t; i < 6 * CG; i += 256) wT[i] = W4[i];
    int base = blockIdx.x * NPB;
    int lastn = min(base + NPB, N) - 1;
    int eBeg = rowptr[base];
    int eEnd = rowptr[lastn] + cnt[lastn];
    int M = eEnd - eBeg;
    bool useL = (M <= ECAP1);
    if (useL) {
        for (int i = t; i < M; i += 256) eLDS[i] = e2[eBeg + i];
    }
    __syncthreads();
    {
        const float2* x2 = (const float2*)x;
        int ew = t & 3;
        int nl0 = t >> 2;
#pragma unroll 1
        for (int it = 0; it < 4; ++it) {
            int nl = it * 64 + nl0;
            int n = base + nl;
            float a0 = 0, a1 = 0, a2 = 0, a3 = 0, a4 = 0, a5 = 0;
            float di = 0.f;
            if (n < N) {
                di = dinv[n];
                int beg = rowptr[n], end = beg + cnt[n];
                if (ew == 0) {
                    size_t b3 = (size_t)n * 3;
                    float2 p0 = x2[b3], p1 = x2[b3 + 1], p2 = x2[b3 + 2];
                    a0 = di * p0.x; a1 = di * p0.y; a2 = di * p1.x;
                    a3 = di * p1.y; a4 = di * p2.x; a5 = di * p2.y;
                }
                if (useL) {
                    int r = beg - eBeg + ew, re = end - eBeg;
                    for (; r + 4 < re; r += 8) {
                        int2 pa = eLDS[r], pb = eLDS[r + 4];
                        size_t sa = (size_t)pa.x * 3, sb = (size_t)pb.x * 3;
                        float2 qa0 = x2[sa], qa1 = x2[sa + 1], qa2 = x2[sa + 2];
                        float2 qb0 = x2[sb], qb1 = x2[sb + 1], qb2 = x2[sb + 2];
                        __builtin_amdgcn_sched_barrier(0);
                        float wa = __int_as_float(pa.y), wb = __int_as_float(pb.y);
                        a0 = fmaf(wa, qa0.x, a0); a1 = fmaf(wa, qa0.y, a1);
                        a2 = fmaf(wa, qa1.x, a2); a3 = fmaf(wa, qa1.y, a3);
                        a4 = fmaf(wa, qa2.x, a4); a5 = fmaf(wa, qa2.y, a5);
                        a0 = fmaf(wb, qb0.x, a0); a1 = fmaf(wb, qb0.y, a1);
                        a2 = fmaf(wb, qb1.x, a2); a3 = fmaf(wb, qb1.y, a3);
                        a4 = fmaf(wb, qb2.x, a4); a5 = fmaf(wb, qb2.y, a5);
                    }
                    if (r < re) {
                        int2 pa = eLDS[r];
                        size_t sa = (size_t)pa.x * 3;
                        float2 qa0 = x2[sa], qa1 = x2[sa + 1], qa2 = x2[sa + 2];
                        float wa = __int_as_float(pa.y);
                        a0 = fmaf(wa, qa0.x, a0); a1 = fmaf(wa, qa0.y, a1);
                        a2 = fmaf(wa, qa1.x, a2); a3 = fmaf(wa, qa1.y, a3);
                        a4 = fmaf(wa, qa2.x, a4); a5 = fmaf(wa, qa2.y, a5);
                    }
                } else {
                    for (int e = beg + ew; e < end; e += 4) {
                        int2 pa = e2[e];
                        size_t sa = (size_t)pa.x * 3;
                        float2 qa0 = x2[sa], qa1 = x2[sa + 1], qa2 = x2[sa + 2];
                        float wa = __int_as_float(pa.y);
                        a0 = fmaf(wa, qa0.x, a0); a1 = fmaf(wa, qa0.y, a1);
                        a2 = fmaf(wa, qa1.x, a2); a3 = fmaf(wa, qa1.y, a3);
                        a4 = fmaf(wa, qa2.x, a4); a5 = fmaf(wa, qa2.y, a5);
                    }
                }
            }
#pragma unroll
            for (int m = 1; m < 4; m <<= 1) {
                a0 += __shfl_xor(a0, m); a1 += __shfl_xor(a1, m);
                a2 += __shfl_xor(a2, m); a3 += __shfl_xor(a3, m);
                a4 += __shfl_xor(a4, m); a5 += __shfl_xor(a5, m);
            }
            if (ew == 0 && n < N) {
                int o = nl * 6;
                inT[o + 0] = di * a0; inT[o + 1] = di * a1; inT[o + 2] = di * a2;
                inT[o + 3] = di * a3; inT[o + 4] = di * a4; inT[o + 5] = di * a5;
            }
        }
    }
    __syncthreads();
    int gi = t % CG, r0 = t / CG, c0 = gi * 4;
    int nrows = min(NPB, N - base);
    float4 s = {0, 0, 0, 0}, s2 = {0, 0, 0, 0};
    for (int r = r0; r < nrows; r += RPB) {
        const float* row = inT + r * 6;
        float4 acc = {0, 0, 0, 0};
#pragma unroll
        for (int k = 0; k < 6; ++k) acc = f4fma(row[k], wT[k * CG + gi], acc);
        sth4(hout + (size_t)(base + r) * COUT + gi * 4, acc);
        s = f4add(s, acc);
        s2.x = fmaf(acc.x, acc.x, s2.x);
        s2.y = fmaf(acc.y, acc.y, s2.y);
        s2.z = fmaf(acc.z, acc.z, s2.z);
        s2.w = fmaf(acc.w, acc.w, s2.w);
    }
    red[t] = s;
    for (int hh = RPB / 2; hh > 0; hh >>= 1) {
        __syncthreads();
        if (r0 < hh) red[t] = f4add(red[t], red[t + hh * CG]);
    }
    if (r0 == 0) {
        float4 a = red[t];
        atomicAdd(&sums[c0 + 0], a.x); atomicAdd(&sums[c0 + 1], a.y);
        atomicAdd(&sums[c0 + 2], a.z); atomicAdd(&sums[c0 + 3], a.w);
    }
    __syncthreads();
    red[t] = s2;
    for (int hh = RPB / 2; hh > 0; hh >>= 1) {
        __syncthreads();
        if (r0 < hh) red[t] = f4add(red[t], red[t + hh * CG]);
    }
    if (r0 == 0) {
        float4 b = red[t];
        atomicAdd(&sumsq[c0 + 0], b.x); atomicAdd(&sumsq[c0 + 1], b.y);
        atomicAdd(&sumsq[c0 + 2], b.z); atomicAdd(&sumsq[c0 + 3], b.w);
    }
}

// ---------------- fused layer: gather(+BN_prev+ReLU) fp16 rows + mm CIN->COUT + stats ----------------
// Best-measured structure (r6, 751.9 us): edge records staged in LDS, rounds of 8 with
// 8 row loads in flight per lane group, cached loads, fp16 storage.

template <int CIN, int COUT, int NPB>
__global__ __launch_bounds__(256, 4) void k_layer(
    const int* __restrict__ rowptr, const int* __restrict__ cnt,
    const int2* __restrict__ e2, const float* __restrict__ dinv,
    const ushort_t* __restrict__ hin,
    const float* __restrict__ sums_in, const float* __restrict__ sumsq_in,
    const float* __restrict__ gam, const float* __restrict__ bet,
    const float* __restrict__ W, ushort_t* __restrict__ hout,
    float* __restrict__ sums_out, float* __restrict__ sumsq_out,
    int N, float invN) {
    constexpr int TPN = CIN / 4;      // threads cooperating on one node (gather)
    constexpr int PAD = TPN + 1;      // padded row stride in float4
    constexpr int ITER1 = NPB * TPN / 256;
    constexpr int NPI = 256 / TPN;    // nodes gathered per iteration
    constexpr int CG = COUT / 4;
    constexpr int RPB = 256 / CG;
    constexpr int ECAP = 2048;
    __shared__ float4 inT4[NPB * PAD];
    __shared__ float4 red[256];
    __shared__ int2 eLDS[ECAP];
    int t = threadIdx.x;
    const float4* W4 = (const float4*)W;
    int base = blockIdx.x * NPB;
    int lastn = min(base + NPB, N) - 1;
    int eBeg = rowptr[base];
    int eEnd = rowptr[lastn] + cnt[lastn];
    int M = eEnd - eBeg;
    bool useL = (M <= ECAP);
    if (useL) {
        for (int i = t; i < M; i += 256) eLDS[i] = e2[eBeg + i];
    }
    __syncthreads();
    // ---- phase 1: gather with BN_prev+ReLU applied to loaded fp16 values ----
    {
        int c4 = t % TPN;
        float4 sm = reinterpret_cast<const float4*>(sums_in)[c4];
        float4 sq = reinterpret_cast<const float4*>(sumsq_in)[c4];
        float4 ga = reinterpret_cast<const float4*>(gam)[c4];
        float4 bt = reinterpret_cast<const float4*>(bet)[c4];
        float4 sc, sh;
        bnparam(sm.x, sq.x, ga.x, bt.x, invN, sc.x, sh.x);
        bnparam(sm.y, sq.y, ga.y, bt.y, invN, sc.y, sh.y);
        bnparam(sm.z, sq.z, ga.z, bt.z, invN, sc.z, sh.z);
        bnparam(sm.w, sq.w, ga.w, bt.w, invN, sc.w, sh.w);
        const ushort_t* hu = hin;
        int co = c4 * 4;  // channel offset of this lane within the row
#pragma unroll
        for (int it = 0; it < ITER1; ++it) {
            int nl = it * NPI + t / TPN;
            int n = base + nl;
            if (n < N) {
                int beg = rowptr[n], end = beg + cnt[n];
                float di = dinv[n];
                float4 acc = f4scale(di, bnrelu4(ldh4(hu + (size_t)n * CIN + co), sc, sh));
                if (useL) {
                    int r = beg - eBeg, re = end - eBeg;
                    // rounds of 8: idx from LDS (cheap), 8 row loads in flight
                    for (; r + 7 < re; r += 8) {
                        int2 p0 = eLDS[r],     p1 = eLDS[r + 1];
                        int2 p2_ = eLDS[r + 2], p3_ = eLDS[r + 3];
                        int2 p4 = eLDS[r + 4], p5 = eLDS[r + 5];
                        int2 p6 = eLDS[r + 6], p7 = eLDS[r + 7];
                        float4 v0 = ldh4(hu + (size_t)p0.x * CIN + co);
                        float4 v1 = ldh4(hu + (size_t)p1.x * CIN + co);
                        float4 v2 = ldh4(hu + (size_t)p2_.x * CIN + co);
                        float4 v3 = ldh4(hu + (size_t)p3_.x * CIN + co);
                        float4 v4 = ldh4(hu + (size_t)p4.x * CIN + co);
                        float4 v5 = ldh4(hu + (size_t)p5.x * CIN + co);
                        float4 v6 = ldh4(hu + (size_t)p6.x * CIN + co);
                        float4 v7 = ldh4(hu + (size_t)p7.x * CIN + co);
                        __builtin_amdgcn_sched_barrier(0);
                        acc = f4fma(__int_as_float(p0.y), bnrelu4(v0, sc, sh), acc);
                        acc = f4fma(__int_as_float(p1.y), bnrelu4(v1, sc, sh), acc);
                        acc = f4fma(__int_as_float(p2_.y), bnrelu4(v2, sc, sh), acc);
                        acc = f4fma(__int_as_float(p3_.y), bnrelu4(v3, sc, sh), acc);
                        acc = f4fma(__int_as_float(p4.y), bnrelu4(v4, sc, sh), acc);
                        acc = f4fma(__int_as_float(p5.y), bnrelu4(v5, sc, sh), acc);
                        acc = f4fma(__int_as_float(p6.y), bnrelu4(v6, sc, sh), acc);
                        acc = f4fma(__int_as_float(p7.y), bnrelu4(v7, sc, sh), acc);
                    }
                    for (; r + 3 < re; r += 4) {
                        int2 p0 = eLDS[r], p1 = eLDS[r + 1];
                        int2 p2_ = eLDS[r + 2], p3_ = eLDS[r + 3];
                        float4 v0 = ldh4(hu + (size_t)p0.x * CIN + co);
                        float4 v1 = ldh4(hu + (size_t)p1.x * CIN + co);
                        float4 v2 = ldh4(hu + (size_t)p2_.x * CIN + co);
                        float4 v3 = ldh4(hu + (size_t)p3_.x * CIN + co);
                        __builtin_amdgcn_sched_barrier(0);
                        acc = f4fma(__int_as_float(p0.y), bnrelu4(v0, sc, sh), acc);
                        acc = f4fma(__int_as_float(p1.y), bnrelu4(v1, sc, sh), acc);
                        acc = f4fma(__int_as_float(p2_.y), bnrelu4(v2, sc, sh), acc);
                        acc = f4fma(__int_as_float(p3_.y), bnrelu4(v3, sc, sh), acc);
                    }
                    for (; r < re; ++r) {
                        int2 p0 = eLDS[r];
                        acc = f4fma(__int_as_float(p0.y),
                                    bnrelu4(ldh4(hu + (size_t)p0.x * CIN + co), sc, sh), acc);
                    }
                } else {
                    // overflow fallback (astronomically rare): plain global path
                    for (int e = beg; e < end; ++e) {
                        int2 p0 = e2[e];
                        acc = f4fma(__int_as_float(p0.y),
                                    bnrelu4(ldh4(hu + (size_t)p0.x * CIN + co), sc, sh), acc);
                    }
                }
                inT4[nl * PAD + c4] = f4scale(di, acc);
            }
        }
    }
    __syncthreads();
    // ---- phase 2: mm from LDS (padded fp32 rows), W from global, fp16 store ----
    int gi = t % CG, r0 = t / CG, c0 = gi * 4;
    int nrows = min(NPB, N - base);
    float4 s = {0, 0, 0, 0}, s2 = {0, 0, 0, 0};
    for (int r = r0; r < nrows; r += RPB) {
        const float* row = (const float*)(inT4 + r * PAD);
        float4 acc = {0, 0, 0, 0};
#pragma unroll 8
        for (int k = 0; k < CIN; ++k) acc = f4fma(row[k], W4[k * CG + gi], acc);
        sth4(hout + (size_t)(base + r) * COUT + gi * 4, acc);
        s = f4add(s, acc);
        s2.x = fmaf(acc.x, acc.x, s2.x);
        s2.y = fmaf(acc.y, acc.y, s2.y);
        s2.z = fmaf(acc.z, acc.z, s2.z);
        s2.w = fmaf(acc.w, acc.w, s2.w);
    }
    red[t] = s;
    for (int hh = RPB / 2; hh > 0; hh >>= 1) {
        __syncthreads();
        if (r0 < hh) red[t] = f4add(red[t], red[t + hh * CG]);
    }
    if (r0 == 0) {
        float4 a = red[t];
        atomicAdd(&sums_out[c0 + 0], a.x); atomicAdd(&sums_out[c0 + 1], a.y);
        atomicAdd(&sums_out[c0 + 2], a.z); atomicAdd(&sums_out[c0 + 3], a.w);
    }
    __syncthreads();
    red[t] = s2;
    for (int hh = RPB / 2; hh > 0; hh >>= 1) {
        __syncthreads();
        if (r0 < hh) red[t] = f4add(red[t], red[t + hh * CG]);
    }
    if (r0 == 0) {
        float4 b = red[t];
        atomicAdd(&sumsq_out[c0 + 0], b.x); atomicAdd(&sumsq_out[c0 + 1], b.y);
        atomicAdd(&sumsq_out[c0 + 2], b.z); atomicAdd(&sumsq_out[c0 + 3], b.w);
    }
}

// ---------------- head matmul (pool @ Wf1) + stats, LDS-tiled ----------------

template <int CIN, int COUT, int ROWS>
__global__ __launch_bounds__(256) void k_mm_stats(
    const float* __restrict__ in, const float* __restrict__ W,
    float* __restrict__ out, float* __restrict__ sums,
    float* __restrict__ sumsq, int N) {
    constexpr int CG = COUT / 4;
    constexpr int RPB = 256 / CG;
    __shared__ float4 inT4[ROWS * CIN / 4];
    float* inT = (float*)inT4;
    __shared__ float4 wT[CIN * CG];
    __shared__ float4 red[256];
    int t = threadIdx.x;
    const float4* W4 = reinterpret_cast<const float4*>(W);
    for (int i = t; i < CIN * CG; i += 256) wT[i] = W4[i];
    int base = blockIdx.x * ROWS;
    int nrows = min(ROWS, N - base);
    {
        const float4* in4 = reinterpret_cast<const float4*>(in + (size_t)base * CIN);
        int tot = nrows * (CIN / 4);
        for (int i = t; i < tot; i += 256) inT4[i] = in4[i];
    }
    __syncthreads();
    int gi = t % CG, r0 = t / CG, c0 = gi * 4;
    float4 s = {0, 0, 0, 0}, s2 = {0, 0, 0, 0};
    for (int r = r0; r < nrows; r += RPB) {
        const float* row = inT + r * CIN;
        float4 acc = {0, 0, 0, 0};
#pragma unroll
        for (int k = 0; k < CIN; ++k) acc = f4fma(row[k], wT[k * CG + gi], acc);
        reinterpret_cast<float4*>(out + (size_t)(base + r) * COUT)[gi] = acc;
        s = f4add(s, acc);
        s2.x = fmaf(acc.x, acc.x, s2.x);
        s2.y = fmaf(acc.y, acc.y, s2.y);
        s2.z = fmaf(acc.z, acc.z, s2.z);
        s2.w = fmaf(acc.w, acc.w, s2.w);
    }
    red[t] = s;
    for (int hh = RPB / 2; hh > 0; hh >>= 1) {
        __syncthreads();
        if (r0 < hh) red[t] = f4add(red[t], red[t + hh * CG]);
    }
    if (r0 == 0) {
        float4 a = red[t];
        atomicAdd(&sums[c0 + 0], a.x); atomicAdd(&sums[c0 + 1], a.y);
        atomicAdd(&sums[c0 + 2], a.z); atomicAdd(&sums[c0 + 3], a.w);
    }
    __syncthreads();
    red[t] = s2;
    for (int hh = RPB / 2; hh > 0; hh >>= 1) {
        __syncthreads();
        if (r0 < hh) red[t] = f4add(red[t], red[t + hh * CG]);
    }
    if (r0 == 0) {
        float4 b = red[t];
        atomicAdd(&sumsq[c0 + 0], b.x); atomicAdd(&sumsq[c0 + 1], b.y);
        atomicAdd(&sumsq[c0 + 2], b.z); atomicAdd(&sumsq[c0 + 3], b.w);
    }
}

// ---------------- segmented segment_max with fused BN+ReLU (batch is sorted) ----------------

__global__ void k_segmax_bn(const ushort_t* __restrict__ h, const int* __restrict__ batch,
                            const float* __restrict__ sums, const float* __restrict__ sumsq,
                            const float* __restrict__ gam, const float* __restrict__ bet,
                            float* __restrict__ pool, int N, float invN) {
    int t = threadIdx.x;
    int c = t & 127;
    int sub = t >> 7;
    int base = blockIdx.x * 64 + sub * 32;
    if (base >= N) return;
    float sc, sh;
    bnparam(sums[c], sumsq[c], gam[c], bet[c], invN, sc, sh);
    int cur = batch[base];
    float h0 = __half2float(*reinterpret_cast<const __half*>(&h[(size_t)base * 128 + c]));
    float mx = fmaxf(fmaf(sc, h0, sh), 0.f);
    int lim = min(32, N - base);
    for (int i = 1; i < lim; ++i) {
        int n = base + i;
        int b = batch[n];
        float hv = __half2float(*reinterpret_cast<const __half*>(&h[(size_t)n * 128 + c]));
        float v = fmaxf(fmaf(sc, hv, sh), 0.f);
        if (b != cur) {
            atomicMax(reinterpret_cast<int*>(pool) + (cur << 7) + c, __float_as_int(mx));
            cur = b; mx = v;
        } else {
            mx = fmaxf(mx, v);
        }
    }
    atomicMax(reinterpret_cast<int*>(pool) + (cur << 7) + c, __float_as_int(mx));
}

// ---------------- head: BN4+ReLU on load, FC2, row-L2-normalize ----------------

__global__ void k_head(const float* __restrict__ Z, const float* __restrict__ sums,
                       const float* __restrict__ sumsq, const float* __restrict__ gam,
                       const float* __restrict__ bet, const float* __restrict__ Wf2,
                       const float* __restrict__ bf2, float* __restrict__ out) {
    int g = blockIdx.x, c = threadIdx.x;  // 64 threads = 1 wave
    __shared__ float row[128];
    const float invG = 1.0f / (float)NG;
    for (int j = c; j < 128; j += 64) {
        float sc, sh;
        bnparam(sums[j], sumsq[j], gam[j], bet[j], invG, sc, sh);
        row[j] = fmaxf(fmaf(sc, Z[(g << 7) + j], sh), 0.f);
    }
    __syncthreads();
    float acc = bf2[c];
#pragma unroll
    for (int k = 0; k < 128; ++k) acc = fmaf(row[k], Wf2[k * 64 + c], acc);
    float ss = acc * acc;
#pragma unroll
    for (int off = 32; off; off >>= 1) ss += __shfl_xor(ss, off);
    out[(g << 6) + c] = acc / fmaxf(sqrtf(ss), 1e-12f);
}

// ---------------- launch ----------------

extern "C" void kernel_launch(void* const* d_in, const int* in_sizes, int n_in,
                              void* d_out, int out_size, void* d_ws, size_t ws_size,
                              hipStream_t stream) {
    const float* x    = (const float*)d_in[0];
    const int*   src  = (const int*)d_in[1];
    const int*   dst  = (const int*)d_in[2];
    const int*   batch= (const int*)d_in[3];
    const float* W1   = (const float*)d_in[4];   // b1 cancels in BN
    const float* g1   = (const float*)d_in[6];
    const float* be1  = (const float*)d_in[7];
    const float* W2   = (const float*)d_in[8];   // b2 cancels
    const float* g2   = (const float*)d_in[10];
    const float* be2  = (const float*)d_in[11];
    const float* W3   = (const float*)d_in[12];  // b3 cancels
    const float* g3   = (const float*)d_in[14];
    const float* be3  = (const float*)d_in[15];
    const float* Wf1  = (const float*)d_in[16];  // bf1 cancels
    const float* g4   = (const float*)d_in[18];
    const float* be4  = (const float*)d_in[19];
    const float* Wf2  = (const float*)d_in[20];
    const float* bf2  = (const float*)d_in[21];
    float* out = (float*)d_out;

    const int N = in_sizes[0] / 6;
    const int E = in_sizes[1];
    const int nScanBlocks = (N + SCAN_T * SCAN_I - 1) / (SCAN_T * SCAN_I);

    // workspace carve-up
    char* ws = (char*)d_ws;
    size_t off = 0;
    auto carve = [&](size_t bytes) {
        void* p = ws + off;
        off += (bytes + 255) & ~(size_t)255;
        return p;
    };
    int*     cnt    = (int*)carve((size_t)N * 4);
    float*   dinv   = (float*)carve((size_t)N * 4);
    int*     rowptr = (int*)carve((size_t)N * 4);
    int*     fill   = (int*)carve((size_t)N * 4);
    int*     bsum   = (int*)carve((size_t)4096 * 4);
    int2*    e2     = (int2*)carve((size_t)E * 8);          // packed (src, dinv[src])
    ushort_t* H1    = (ushort_t*)carve((size_t)N * 32 * 2); // layer-1 output (fp16)
    ushort_t* H2    = (ushort_t*)carve((size_t)N * 64 * 2); // layer-2 output (fp16)
    ushort_t* H3    = (ushort_t*)carve((size_t)N * 128 * 2);// layer-3 output (fp16)
    float*   stats  = (float*)carve(704 * 4);
    float*   pool   = (float*)carve((size_t)NG * 128 * 4);
    float*   Z      = (float*)carve((size_t)NG * 128 * 4);
    float* s1 = stats;        // L1 sums/sumsq (32+32)
    float* s2 = stats + 64;   // L2 (64+64)
    float* s3 = stats + 192;  // L3 (128+128)
    float* s4 = stats + 448;  // head (128+128)

    const float invN = 1.0f / (float)N;

    // ---- build dst-sorted CSR (once; reused by all 3 layers) ----
    hipMemsetAsync(cnt, 0, (size_t)N * 4, stream);
    hipMemsetAsync(fill, 0, (size_t)N * 4, stream);
    hipMemsetAsync(stats, 0, 704 * 4, stream);
    hipMemsetAsync(pool, 0, (size_t)NG * 128 * 4, stream);
    k_count<<<(E + 255) / 256, 256, 0, stream>>>(dst, cnt, E);
    k_dinv<<<(N + 255) / 256, 256, 0, stream>>>(cnt, dinv, N);
    k_scan1<<<nScanBlocks, SCAN_T, 0, stream>>>(cnt, rowptr, bsum, N);
    k_scan2<<<1, SCAN_T, 0, stream>>>(bsum, nScanBlocks);
    k_scan3<<<nScanBlocks, SCAN_T, 0, stream>>>(rowptr, bsum, N);
    k_bucket<<<(E + 255) / 256, 256, 0, stream>>>(src, dst, dinv, rowptr, fill, e2, E);

    // ---- layer 1 fused: edge-parallel gather x (C=6) + mm 6->32 + stats1 -> H1 (fp16) ----
    k_layer1<32><<<(N + 255) / 256, 256, 0, stream>>>(
        rowptr, cnt, e2, dinv, x, W1, H1, s1, s1 + 32, N);

    // ---- layer 2 fused: gather bnrelu1(H1) (C=32, fp16) + mm 32->64 + stats2 -> H2 (fp16) ----
    k_layer<32, 64, 64><<<(N + 63) / 64, 256, 0, stream>>>(
        rowptr, cnt, e2, dinv, H1, s1, s1 + 32, g1, be1, W2, H2,
        s2, s2 + 64, N, invN);

    // ---- layer 3 fused: gather bnrelu2(H2) (C=64, fp16) + mm 64->128 + stats3 -> H3 (fp16) ----
    k_layer<64, 128, 64><<<(N + 63) / 64, 256, 0, stream>>>(
        rowptr, cnt, e2, dinv, H2, s2, s2 + 64, g2, be2, W3, H3,
        s3, s3 + 128, N, invN);

    // ---- pooling: segmented segment_max with fused BN3+ReLU ----
    k_segmax_bn<<<(N + 63) / 64, 256, 0, stream>>>(H3, batch, s3, s3 + 128, g3, be3, pool, N, invN);

    // ---- head: FC1 (+stats4), then BN4+ReLU+FC2+normalize ----
    k_mm_stats<128, 128, 64><<<(NG + 63) / 64, 256, 0, stream>>>(pool, Wf1, Z, s4, s4 + 128, NG);
    k_head<<<NG, 64, 0, stream>>>(Z, s4, s4 + 128, g4, be4, Wf2, bf2, out);
}